// Round 1
// baseline (205.325 us; speedup 1.0000x reference)
//
#include <hip/hip_runtime.h>
#include <math.h>

// Problem constants (fixed by setup_inputs)
#define BS 4
#define NH 8
#define TT 1024         // T = 32*32
#define WROWS 1536      // 3*NH*CH
#define NOBJ 8
#define NT 65536        // per-bh tensor elems (64*1024)

// Workspace layout (short element offsets)
#define QNT_OFF  0
#define KNT_OFF  2097152
#define VNCS_OFF 4194304
#define QFT_OFF  6291456
#define KFT_OFF  8388608
#define VFT_OFF  10485760

typedef __attribute__((ext_vector_type(8))) short short8;
typedef __attribute__((ext_vector_type(4))) float v4f;

__device__ __forceinline__ short f2bf(float f) {
    unsigned u = __float_as_uint(f);
    u = (u + 0x7FFF + ((u >> 16) & 1)) >> 16;   // RNE
    return (short)u;
}
__device__ __forceinline__ unsigned p2(float a, float b) {
    return (unsigned)(unsigned short)f2bf(a) | ((unsigned)(unsigned short)f2bf(b) << 16);
}

__device__ __forceinline__ void get_region(const float* __restrict__ bb,
                                           int& i0, int& j0, int& hh, int& ww) {
    float x = bb[0], y = bb[1], bw = bb[2], bh = bb[3];
    float i0f = fminf(31.0f, floorf(y * 32.0f));
    float j0f = fminf(31.0f, floorf(x * 32.0f));
    float i1f = i0f + fmaxf(1.0f, ceilf(bh * 32.0f));
    float j1f = j0f + fmaxf(1.0f, ceilf(bw * 32.0f));
    i0 = (int)i0f; j0 = (int)j0f;
    int i1 = min(32, (int)i1f);
    int j1 = min(32, (int)j1f);
    hh = i1 - i0; ww = j1 - j0;
}

__device__ __forceinline__ float rowsum16(float x) {
    x += __shfl_xor(x, 1, 64);
    x += __shfl_xor(x, 2, 64);
    x += __shfl_xor(x, 4, 64);
    x += __shfl_xor(x, 8, 64);
    return x;
}

// ---------------------------------------------------------------------------
// Kernel 1: fused projection + layout conversion to bf16 (unchanged).
// ---------------------------------------------------------------------------
__global__ __launch_bounds__(256)
void fuse_kernel(const float* __restrict__ qkv, const float* __restrict__ nEmb,
                 const float* __restrict__ pEmb, const float* __restrict__ W,
                 short* __restrict__ wsS) {
    __shared__ float WtT[64][68];
    __shared__ float En[64][64];
    __shared__ float Ep[64][64];
    short* sbuf = (short*)&WtT[0][0];   // 64x72 shorts = 9216 B, aliases WtT
    int t0 = blockIdx.x * 64;
    int r0 = blockIdx.y * 64;
    int b  = blockIdx.z;
    int tid = threadIdx.x;
    int half = tid >> 4;
    int q4 = (tid & 15) * 4;
#pragma unroll
    for (int p = 0; p < 4; ++p) {
        int rr = p * 16 + half;
        float4 w4 = *(const float4*)&W[(r0 + rr) * 64 + q4];
        WtT[q4 + 0][rr] = w4.x; WtT[q4 + 1][rr] = w4.y;
        WtT[q4 + 2][rr] = w4.z; WtT[q4 + 3][rr] = w4.w;
        int e = p * 16 + half;
        *(float4*)&En[e][q4] = *(const float4*)&nEmb[(b * 64 + e) * TT + t0 + q4];
        *(float4*)&Ep[e][q4] = *(const float4*)&pEmb[(b * 64 + e) * TT + t0 + q4];
    }
    __syncthreads();
    int tr = tid >> 4, tc = tid & 15;
    float an[4][4] = {{0.f}}, ap[4][4] = {{0.f}};
#pragma unroll 8
    for (int e = 0; e < 64; ++e) {
        float4 w4 = *(const float4*)&WtT[e][tr * 4];
        float4 n4 = *(const float4*)&En[e][tc * 4];
        float4 p4 = *(const float4*)&Ep[e][tc * 4];
        float w[4]  = {w4.x, w4.y, w4.z, w4.w};
        float nn[4] = {n4.x, n4.y, n4.z, n4.w};
        float pp[4] = {p4.x, p4.y, p4.z, p4.w};
#pragma unroll
        for (int i = 0; i < 4; ++i)
#pragma unroll
            for (int j = 0; j < 4; ++j) {
                an[i][j] += w[i] * nn[j];
                ap[i][j] += w[i] * pp[j];
            }
    }
    int sec = (r0 % 192) / 64;          // 0=q 1=k 2=v
    int h = r0 / 192, bh = b * 8 + h;
    float sc = (sec == 0) ? 0.125f : 1.0f;   // fold scale^2 into Q
#pragma unroll
    for (int i = 0; i < 4; ++i) {
        int r = r0 + tr * 4 + i;
        float4 x4 = *(const float4*)&qkv[(b * WROWS + r) * TT + t0 + tc * 4];
        an[i][0] = (an[i][0] + x4.x) * sc; an[i][1] = (an[i][1] + x4.y) * sc;
        an[i][2] = (an[i][2] + x4.z) * sc; an[i][3] = (an[i][3] + x4.w) * sc;
        ap[i][0] = (ap[i][0] + x4.x) * sc; ap[i][1] = (ap[i][1] + x4.y) * sc;
        ap[i][2] = (ap[i][2] + x4.z) * sc; ap[i][3] = (ap[i][3] + x4.w) * sc;
    }
    if (sec == 2) {
        short* Vn = wsS + VNCS_OFF + bh * NT;
#pragma unroll
        for (int i = 0; i < 4; ++i) {
            int c = tr * 4 + i;
            uint2 pk; pk.x = p2(an[i][0], an[i][1]); pk.y = p2(an[i][2], an[i][3]);
            *(uint2*)&Vn[c * TT + t0 + tc * 4] = pk;
        }
        short* dst = wsS + VFT_OFF + bh * NT + t0 * 64;
        __syncthreads();
#pragma unroll
        for (int i = 0; i < 4; ++i)
#pragma unroll
            for (int j = 0; j < 4; ++j)
                sbuf[(tc * 4 + j) * 72 + tr * 4 + i] = f2bf(ap[i][j]);
        __syncthreads();
#pragma unroll
        for (int rep = 0; rep < 2; ++rep) {
            int idx = rep * 256 + tid; int tl = idx >> 3, c8 = idx & 7;
            *(short8*)&dst[tl * 64 + c8 * 8] = *(const short8*)&sbuf[tl * 72 + c8 * 8];
        }
    } else {
        short* dn = wsS + (sec == 0 ? QNT_OFF : KNT_OFF) + bh * NT + t0 * 64;
        short* df = wsS + (sec == 0 ? QFT_OFF : KFT_OFF) + bh * NT + t0 * 64;
        __syncthreads();
#pragma unroll
        for (int i = 0; i < 4; ++i)
#pragma unroll
            for (int j = 0; j < 4; ++j)
                sbuf[(tc * 4 + j) * 72 + tr * 4 + i] = f2bf(an[i][j]);
        __syncthreads();
#pragma unroll
        for (int rep = 0; rep < 2; ++rep) {
            int idx = rep * 256 + tid; int tl = idx >> 3, c8 = idx & 7;
            *(short8*)&dn[tl * 64 + c8 * 8] = *(const short8*)&sbuf[tl * 72 + c8 * 8];
        }
        __syncthreads();
#pragma unroll
        for (int i = 0; i < 4; ++i)
#pragma unroll
            for (int j = 0; j < 4; ++j)
                sbuf[(tc * 4 + j) * 72 + tr * 4 + i] = f2bf(ap[i][j]);
        __syncthreads();
#pragma unroll
        for (int rep = 0; rep < 2; ++rep) {
            int idx = rep * 256 + tid; int tl = idx >> 3, c8 = idx & 7;
            *(short8*)&df[tl * 64 + c8 * 8] = *(const short8*)&sbuf[tl * 72 + c8 * 8];
        }
    }
}

// ---------------------------------------------------------------------------
// Kernel 2: fused null + foreground attention, COLUMN-SPLIT across 2
// wave-groups (512 threads, 8 waves). Fixed-shift softmax (m=0) makes
// partial (l, O) over disjoint column tiles trivially additive:
//   wg0 handles even 64-col tiles, wg1 odd tiles; K/V staging shared.
// Merge is one-sided: wg1 dumps partial O (fp32) into the dead V-staging
// region + l into lbuf; wg0 adds and owns cnt/Oacc/epilogue.
// LDS 57.8 KB -> 2 blocks/CU -> 16 waves/CU (was 8).
// ---------------------------------------------------------------------------
__global__ __launch_bounds__(512, 4)
void attn_fused(const short* __restrict__ wsS, const float* __restrict__ bboxes,
                float* __restrict__ out) {
    __shared__ __align__(16) short lds[27648];
    __shared__ unsigned short tmap[1024];
    __shared__ float lbuf[64];
    short* Ps = lds;            // [128][72] P rows (wave-private); Q staged rows 0..63; Ot aliases
    short* Ks = lds + 9216;     // [2][64][72]  ([s][c])
    short* Vs = lds + 18432;    // [2][64][72]  ([c][s]); fO1 (fp32 merge buf) aliases
    float* fO1 = (float*)(lds + 18432);   // [64][68] floats = 17408 B
    float* Ot  = (float*)lds;             // [64][68] floats (epilogue)

    int rt = blockIdx.x, bh = blockIdx.y;
    int b = bh >> 3, h = bh & 7;
    int t0 = rt * 64;
    int tid = threadIdx.x;
    int w = tid >> 6, lane = tid & 63, ln = lane & 15, qd = lane >> 4;
    int rw = w & 3;             // row-wave: rows 16*rw .. 16*rw+15
    int wg = w >> 2;            // column group: 0 = even tiles, 1 = odd tiles
    const short* QnT = wsS + QNT_OFF + bh * NT;
    const short* KnT = wsS + KNT_OFF + bh * NT;
    const short* Vn  = wsS + VNCS_OFF + bh * NT;
    const short* QfT = wsS + QFT_OFF + bh * NT;
    const short* KfT = wsS + KFT_OFF + bh * NT;
    const short* VfT = wsS + VFT_OFF + bh * NT;
    int scell = tid >> 3, sc8 = tid & 7;   // staging coords: cell 0..63, chunk 0..7
    short* Kb = Ks + wg * 4608;            // this wave-group's K buffer
    short* Vb = Vs + wg * 4608;            // this wave-group's V buffer

    // ================= Phase 1: null attention =================
    *(short8*)&Ps[scell * 72 + sc8 * 8] = *(const short8*)&QnT[(t0 + scell) * 64 + sc8 * 8];
    __syncthreads();
    short8 aq0 = *(const short8*)&Ps[(16 * rw + ln) * 72 + qd * 8];
    short8 aq1 = *(const short8*)&Ps[(16 * rw + ln) * 72 + 32 + qd * 8];
    v4f O[4]; float l[4];
#pragma unroll
    for (int r = 0; r < 4; ++r) l[r] = 0.f;
#pragma unroll
    for (int cc = 0; cc < 4; ++cc) O[cc] = (v4f){0.f, 0.f, 0.f, 0.f};
    short8 kreg[2], vreg[2];
    kreg[0] = *(const short8*)&KnT[scell * 64 + sc8 * 8];
    kreg[1] = *(const short8*)&KnT[(64 + scell) * 64 + sc8 * 8];
    vreg[0] = *(const short8*)&Vn[scell * TT + sc8 * 8];
    vreg[1] = *(const short8*)&Vn[scell * TT + 64 + sc8 * 8];
    for (int it = 0; it < 8; ++it) {        // 2 tiles per iteration (one per wg)
        __syncthreads();
        *(short8*)&Ks[scell * 72 + sc8 * 8]        = kreg[0];
        *(short8*)&Ks[4608 + scell * 72 + sc8 * 8] = kreg[1];
        *(short8*)&Vs[scell * 72 + sc8 * 8]        = vreg[0];   // Vn already [c][t]
        *(short8*)&Vs[4608 + scell * 72 + sc8 * 8] = vreg[1];
        __syncthreads();
        if (it < 7) {
            int s0 = (it + 1) * 128;
            kreg[0] = *(const short8*)&KnT[(s0 + scell) * 64 + sc8 * 8];
            kreg[1] = *(const short8*)&KnT[(s0 + 64 + scell) * 64 + sc8 * 8];
            vreg[0] = *(const short8*)&Vn[scell * TT + s0 + sc8 * 8];
            vreg[1] = *(const short8*)&Vn[scell * TT + s0 + 64 + sc8 * 8];
        }
        v4f S[4];
#pragma unroll
        for (int nn = 0; nn < 4; ++nn) {
            short8 b0 = *(const short8*)&Kb[(nn * 16 + ln) * 72 + qd * 8];
            short8 b1 = *(const short8*)&Kb[(nn * 16 + ln) * 72 + 32 + qd * 8];
            v4f z = (v4f){0.f, 0.f, 0.f, 0.f};
            z = __builtin_amdgcn_mfma_f32_16x16x32_bf16(aq0, b0, z, 0, 0, 0);
            z = __builtin_amdgcn_mfma_f32_16x16x32_bf16(aq1, b1, z, 0, 0, 0);
            S[nn] = z;
        }
#pragma unroll
        for (int r = 0; r < 4; ++r) {
            float e0 = __expf(S[0][r]);
            float e1 = __expf(S[1][r]);
            float e2 = __expf(S[2][r]);
            float e3 = __expf(S[3][r]);
            l[r] += e0 + e1 + e2 + e3;
            int prow = (w * 16 + 4 * qd + r) * 72;
            Ps[prow +  0 + ln] = f2bf(e0);
            Ps[prow + 16 + ln] = f2bf(e1);
            Ps[prow + 32 + ln] = f2bf(e2);
            Ps[prow + 48 + ln] = f2bf(e3);
        }
        short8 ap0 = *(const short8*)&Ps[(w * 16 + ln) * 72 + qd * 8];
        short8 ap1 = *(const short8*)&Ps[(w * 16 + ln) * 72 + 32 + qd * 8];
#pragma unroll
        for (int cc = 0; cc < 4; ++cc) {
            short8 bv0 = *(const short8*)&Vb[(cc * 16 + ln) * 72 + qd * 8];
            short8 bv1 = *(const short8*)&Vb[(cc * 16 + ln) * 72 + 32 + qd * 8];
            O[cc] = __builtin_amdgcn_mfma_f32_16x16x32_bf16(ap0, bv0, O[cc], 0, 0, 0);
            O[cc] = __builtin_amdgcn_mfma_f32_16x16x32_bf16(ap1, bv1, O[cc], 0, 0, 0);
        }
    }
    // keep UNNORMALIZED null partials; merge across wg at epilogue
    v4f Onull[4]; float lnull[4];
#pragma unroll
    for (int r = 0; r < 4; ++r) lnull[r] = rowsum16(l[r]);
#pragma unroll
    for (int cc = 0; cc < 4; ++cc) Onull[cc] = O[cc];

    // ================= Phase 2: foreground objects =================
    __syncthreads();
    *(short8*)&Ps[scell * 72 + sc8 * 8] = *(const short8*)&QfT[(t0 + scell) * 64 + sc8 * 8];
    __syncthreads();
    aq0 = *(const short8*)&Ps[(16 * rw + ln) * 72 + qd * 8];
    aq1 = *(const short8*)&Ps[(16 * rw + ln) * 72 + 32 + qd * 8];
    v4f Oacc[4]; float cnt[4];
#pragma unroll
    for (int r = 0; r < 4; ++r) cnt[r] = 0.f;
#pragma unroll
    for (int cc = 0; cc < 4; ++cc) Oacc[cc] = (v4f){0.f, 0.f, 0.f, 0.f};

    for (int o = 0; o < NOBJ; ++o) {
        int i0, j0, hh, ww;
        get_region(&bboxes[(b * NOBJ + o) * 5], i0, j0, hh, ww);
        int i1 = i0 + hh;
        if (i0 > 2 * rt + 1 || i1 <= 2 * rt) continue;   // uniform per block
        int R = hh * ww;
        for (int idx = tid; idx < R; idx += 512) {
            int ri = idx / ww; int rj = idx - ri * ww;
            tmap[idx] = (unsigned short)((i0 + ri) * 32 + j0 + rj);
        }
        __syncthreads();
#pragma unroll
        for (int r = 0; r < 4; ++r) l[r] = 0.f;
#pragma unroll
        for (int cc = 0; cc < 4; ++cc) O[cc] = (v4f){0.f, 0.f, 0.f, 0.f};
        int nct = (R + 63) >> 6;
        int npair = (nct + 1) >> 1;     // wg1's extra tile (odd nct) fully masked
        {
            int tA = tmap[min(scell, R - 1)];
            int tB = tmap[min(64 + scell, R - 1)];
            kreg[0] = *(const short8*)&KfT[tA * 64 + sc8 * 8];
            kreg[1] = *(const short8*)&KfT[tB * 64 + sc8 * 8];
            vreg[0] = *(const short8*)&VfT[tA * 64 + sc8 * 8];
            vreg[1] = *(const short8*)&VfT[tB * 64 + sc8 * 8];
        }
        for (int p = 0; p < npair; ++p) {
            int sbw = (2 * p + wg) * 64;     // this wave-group's col base
            __syncthreads();
            *(short8*)&Ks[scell * 72 + sc8 * 8]        = kreg[0];
            *(short8*)&Ks[4608 + scell * 72 + sc8 * 8] = kreg[1];
            // rotated transpose scatter into Vs [c][s] (bank-conflict-free)
#pragma unroll
            for (int jj = 0; jj < 8; ++jj) {
                int j = (jj + sc8) & 7;
                Vs[(sc8 * 8 + j) * 72 + scell] = vreg[0][j];
            }
#pragma unroll
            for (int jj = 0; jj < 8; ++jj) {
                int j = (jj + sc8) & 7;
                Vs[4608 + (sc8 * 8 + j) * 72 + scell] = vreg[1][j];
            }
            __syncthreads();
            if (p + 1 < npair) {
                int s0 = (2 * p + 2) * 64;
                int tA = tmap[min(s0 + scell, R - 1)];
                int tB = tmap[min(s0 + 64 + scell, R - 1)];
                kreg[0] = *(const short8*)&KfT[tA * 64 + sc8 * 8];
                kreg[1] = *(const short8*)&KfT[tB * 64 + sc8 * 8];
                vreg[0] = *(const short8*)&VfT[tA * 64 + sc8 * 8];
                vreg[1] = *(const short8*)&VfT[tB * 64 + sc8 * 8];
            }
            v4f S[4];
#pragma unroll
            for (int nn = 0; nn < 4; ++nn) {
                short8 b0 = *(const short8*)&Kb[(nn * 16 + ln) * 72 + qd * 8];
                short8 b1 = *(const short8*)&Kb[(nn * 16 + ln) * 72 + 32 + qd * 8];
                v4f z = (v4f){0.f, 0.f, 0.f, 0.f};
                z = __builtin_amdgcn_mfma_f32_16x16x32_bf16(aq0, b0, z, 0, 0, 0);
                z = __builtin_amdgcn_mfma_f32_16x16x32_bf16(aq1, b1, z, 0, 0, 0);
                S[nn] = z;
            }
            float v0 = (sbw +  0 + ln) < R ? 1.f : 0.f;
            float v1 = (sbw + 16 + ln) < R ? 1.f : 0.f;
            float v2 = (sbw + 32 + ln) < R ? 1.f : 0.f;
            float v3 = (sbw + 48 + ln) < R ? 1.f : 0.f;
#pragma unroll
            for (int r = 0; r < 4; ++r) {
                float e0 = __expf(S[0][r]) * v0;
                float e1 = __expf(S[1][r]) * v1;
                float e2 = __expf(S[2][r]) * v2;
                float e3 = __expf(S[3][r]) * v3;
                l[r] += e0 + e1 + e2 + e3;
                int prow = (w * 16 + 4 * qd + r) * 72;
                Ps[prow +  0 + ln] = f2bf(e0);
                Ps[prow + 16 + ln] = f2bf(e1);
                Ps[prow + 32 + ln] = f2bf(e2);
                Ps[prow + 48 + ln] = f2bf(e3);
            }
            short8 ap0 = *(const short8*)&Ps[(w * 16 + ln) * 72 + qd * 8];
            short8 ap1 = *(const short8*)&Ps[(w * 16 + ln) * 72 + 32 + qd * 8];
#pragma unroll
            for (int cc = 0; cc < 4; ++cc) {
                short8 bv0 = *(const short8*)&Vb[(cc * 16 + ln) * 72 + qd * 8];
                short8 bv1 = *(const short8*)&Vb[(cc * 16 + ln) * 72 + 32 + qd * 8];
                O[cc] = __builtin_amdgcn_mfma_f32_16x16x32_bf16(ap0, bv0, O[cc], 0, 0, 0);
                O[cc] = __builtin_amdgcn_mfma_f32_16x16x32_bf16(ap1, bv1, O[cc], 0, 0, 0);
            }
        }
        // cross-wg merge: wg1 dumps partials, wg0 normalizes & accumulates
        __syncthreads();
        if (wg == 1) {
#pragma unroll
            for (int r = 0; r < 4; ++r) {
                float rs = rowsum16(l[r]);
                int row = 16 * rw + 4 * qd + r;
                if (ln == 0) lbuf[row] = rs;
#pragma unroll
                for (int cc = 0; cc < 4; ++cc)
                    fO1[row * 68 + cc * 16 + ln] = O[cc][r];
            }
        }
        __syncthreads();
        if (wg == 0) {
#pragma unroll
            for (int r = 0; r < 4; ++r) {
                int row = 16 * rw + 4 * qd + r;
                float rs = rowsum16(l[r]) + lbuf[row];
                float inv = 1.0f / rs;
                int t = t0 + row;
                int ti = t >> 5, tj = t & 31;
                bool in = (ti >= i0) && (ti < i1) && (tj >= j0) && (tj < j0 + ww);
                if (in) {
                    cnt[r] += 1.f;
#pragma unroll
                    for (int cc = 0; cc < 4; ++cc)
                        Oacc[cc][r] += (O[cc][r] + fO1[row * 68 + cc * 16 + ln]) * inv;
                }
            }
        }
    }

    // ================= Epilogue: null merge + final select + write =========
    __syncthreads();
    if (wg == 1) {
#pragma unroll
        for (int r = 0; r < 4; ++r) {
            int row = 16 * rw + 4 * qd + r;
            if (ln == 0) lbuf[row] = lnull[r];
#pragma unroll
            for (int cc = 0; cc < 4; ++cc)
                fO1[row * 68 + cc * 16 + ln] = Onull[cc][r];
        }
    }
    __syncthreads();
    if (wg == 0) {
#pragma unroll
        for (int r = 0; r < 4; ++r) {
            int row = 16 * rw + 4 * qd + r;
            float lt = lnull[r] + lbuf[row];
            float invn = 1.0f / lt;
            bool fg = cnt[r] > 0.f;
            float icnt = fg ? 1.0f / cnt[r] : 0.f;
#pragma unroll
            for (int cc = 0; cc < 4; ++cc) {
                float vnull = (Onull[cc][r] + fO1[row * 68 + cc * 16 + ln]) * invn;
                float val = fg ? Oacc[cc][r] * icnt : vnull;
                Ot[(cc * 16 + ln) * 68 + row] = val;
            }
        }
    }
    __syncthreads();
    int obase = (b * 512 + h * 64) * TT + t0;
#pragma unroll
    for (int rep = 0; rep < 2; ++rep) {
        int idx = rep * 512 + tid; int c = idx >> 4, t4 = (idx & 15) * 4;
        *(float4*)&out[obase + c * TT + t4] = *(float4*)&Ot[c * 68 + t4];
    }
}

extern "C" void kernel_launch(void* const* d_in, const int* in_sizes, int n_in,
                              void* d_out, int out_size, void* d_ws, size_t ws_size,
                              hipStream_t stream) {
    const float* qkv    = (const float*)d_in[0];
    const float* bboxes = (const float*)d_in[1];
    const float* nEmb   = (const float*)d_in[2];
    const float* pEmb   = (const float*)d_in[3];
    const float* W      = (const float*)d_in[4];
    short* wsS = (short*)d_ws;
    float* out = (float*)d_out;

    fuse_kernel<<<dim3(16, 24, 4), 256, 0, stream>>>(qkv, nEmb, pEmb, W, wsS);
    attn_fused<<<dim3(16, 32), 512, 0, stream>>>(wsS, bboxes, out);
}

// Round 2
// 204.226 us; speedup vs baseline: 1.0054x; 1.0054x over previous
//
#include <hip/hip_runtime.h>
#include <math.h>

// Problem constants (fixed by setup_inputs)
#define BS 4
#define NH 8
#define TT 1024         // T = 32*32
#define WROWS 1536      // 3*NH*CH
#define NOBJ 8
#define NT 65536        // per-bh tensor elems (64*1024)

// Workspace layout (short element offsets)
#define QNT_OFF  0
#define KNT_OFF  2097152
#define VNCS_OFF 4194304
#define QFT_OFF  6291456
#define KFT_OFF  8388608
#define VFT_OFF  10485760

typedef __attribute__((ext_vector_type(8))) short short8;
typedef __attribute__((ext_vector_type(4))) float v4f;

__device__ __forceinline__ short f2bf(float f) {
    unsigned u = __float_as_uint(f);
    u = (u + 0x7FFF + ((u >> 16) & 1)) >> 16;   // RNE
    return (short)u;
}
__device__ __forceinline__ unsigned p2(float a, float b) {
    return (unsigned)(unsigned short)f2bf(a) | ((unsigned)(unsigned short)f2bf(b) << 16);
}

__device__ __forceinline__ void get_region(const float* __restrict__ bb,
                                           int& i0, int& j0, int& hh, int& ww) {
    float x = bb[0], y = bb[1], bw = bb[2], bh = bb[3];
    float i0f = fminf(31.0f, floorf(y * 32.0f));
    float j0f = fminf(31.0f, floorf(x * 32.0f));
    float i1f = i0f + fmaxf(1.0f, ceilf(bh * 32.0f));
    float j1f = j0f + fmaxf(1.0f, ceilf(bw * 32.0f));
    i0 = (int)i0f; j0 = (int)j0f;
    int i1 = min(32, (int)i1f);
    int j1 = min(32, (int)j1f);
    hh = i1 - i0; ww = j1 - j0;
}

__device__ __forceinline__ float rowsum16(float x) {
    x += __shfl_xor(x, 1, 64);
    x += __shfl_xor(x, 2, 64);
    x += __shfl_xor(x, 4, 64);
    x += __shfl_xor(x, 8, 64);
    return x;
}

// ---------------------------------------------------------------------------
// Kernel 1: fused projection + layout conversion to bf16 (unchanged).
// ---------------------------------------------------------------------------
__global__ __launch_bounds__(256)
void fuse_kernel(const float* __restrict__ qkv, const float* __restrict__ nEmb,
                 const float* __restrict__ pEmb, const float* __restrict__ W,
                 short* __restrict__ wsS) {
    __shared__ float WtT[64][68];
    __shared__ float En[64][64];
    __shared__ float Ep[64][64];
    short* sbuf = (short*)&WtT[0][0];   // 64x72 shorts = 9216 B, aliases WtT
    int t0 = blockIdx.x * 64;
    int r0 = blockIdx.y * 64;
    int b  = blockIdx.z;
    int tid = threadIdx.x;
    int half = tid >> 4;
    int q4 = (tid & 15) * 4;
#pragma unroll
    for (int p = 0; p < 4; ++p) {
        int rr = p * 16 + half;
        float4 w4 = *(const float4*)&W[(r0 + rr) * 64 + q4];
        WtT[q4 + 0][rr] = w4.x; WtT[q4 + 1][rr] = w4.y;
        WtT[q4 + 2][rr] = w4.z; WtT[q4 + 3][rr] = w4.w;
        int e = p * 16 + half;
        *(float4*)&En[e][q4] = *(const float4*)&nEmb[(b * 64 + e) * TT + t0 + q4];
        *(float4*)&Ep[e][q4] = *(const float4*)&pEmb[(b * 64 + e) * TT + t0 + q4];
    }
    __syncthreads();
    int tr = tid >> 4, tc = tid & 15;
    float an[4][4] = {{0.f}}, ap[4][4] = {{0.f}};
#pragma unroll 8
    for (int e = 0; e < 64; ++e) {
        float4 w4 = *(const float4*)&WtT[e][tr * 4];
        float4 n4 = *(const float4*)&En[e][tc * 4];
        float4 p4 = *(const float4*)&Ep[e][tc * 4];
        float w[4]  = {w4.x, w4.y, w4.z, w4.w};
        float nn[4] = {n4.x, n4.y, n4.z, n4.w};
        float pp[4] = {p4.x, p4.y, p4.z, p4.w};
#pragma unroll
        for (int i = 0; i < 4; ++i)
#pragma unroll
            for (int j = 0; j < 4; ++j) {
                an[i][j] += w[i] * nn[j];
                ap[i][j] += w[i] * pp[j];
            }
    }
    int sec = (r0 % 192) / 64;          // 0=q 1=k 2=v
    int h = r0 / 192, bh = b * 8 + h;
    float sc = (sec == 0) ? 0.125f : 1.0f;   // fold scale^2 into Q
#pragma unroll
    for (int i = 0; i < 4; ++i) {
        int r = r0 + tr * 4 + i;
        float4 x4 = *(const float4*)&qkv[(b * WROWS + r) * TT + t0 + tc * 4];
        an[i][0] = (an[i][0] + x4.x) * sc; an[i][1] = (an[i][1] + x4.y) * sc;
        an[i][2] = (an[i][2] + x4.z) * sc; an[i][3] = (an[i][3] + x4.w) * sc;
        ap[i][0] = (ap[i][0] + x4.x) * sc; ap[i][1] = (ap[i][1] + x4.y) * sc;
        ap[i][2] = (ap[i][2] + x4.z) * sc; ap[i][3] = (ap[i][3] + x4.w) * sc;
    }
    if (sec == 2) {
        short* Vn = wsS + VNCS_OFF + bh * NT;
#pragma unroll
        for (int i = 0; i < 4; ++i) {
            int c = tr * 4 + i;
            uint2 pk; pk.x = p2(an[i][0], an[i][1]); pk.y = p2(an[i][2], an[i][3]);
            *(uint2*)&Vn[c * TT + t0 + tc * 4] = pk;
        }
        short* dst = wsS + VFT_OFF + bh * NT + t0 * 64;
        __syncthreads();
#pragma unroll
        for (int i = 0; i < 4; ++i)
#pragma unroll
            for (int j = 0; j < 4; ++j)
                sbuf[(tc * 4 + j) * 72 + tr * 4 + i] = f2bf(ap[i][j]);
        __syncthreads();
#pragma unroll
        for (int rep = 0; rep < 2; ++rep) {
            int idx = rep * 256 + tid; int tl = idx >> 3, c8 = idx & 7;
            *(short8*)&dst[tl * 64 + c8 * 8] = *(const short8*)&sbuf[tl * 72 + c8 * 8];
        }
    } else {
        short* dn = wsS + (sec == 0 ? QNT_OFF : KNT_OFF) + bh * NT + t0 * 64;
        short* df = wsS + (sec == 0 ? QFT_OFF : KFT_OFF) + bh * NT + t0 * 64;
        __syncthreads();
#pragma unroll
        for (int i = 0; i < 4; ++i)
#pragma unroll
            for (int j = 0; j < 4; ++j)
                sbuf[(tc * 4 + j) * 72 + tr * 4 + i] = f2bf(an[i][j]);
        __syncthreads();
#pragma unroll
        for (int rep = 0; rep < 2; ++rep) {
            int idx = rep * 256 + tid; int tl = idx >> 3, c8 = idx & 7;
            *(short8*)&dn[tl * 64 + c8 * 8] = *(const short8*)&sbuf[tl * 72 + c8 * 8];
        }
        __syncthreads();
#pragma unroll
        for (int i = 0; i < 4; ++i)
#pragma unroll
            for (int j = 0; j < 4; ++j)
                sbuf[(tc * 4 + j) * 72 + tr * 4 + i] = f2bf(ap[i][j]);
        __syncthreads();
#pragma unroll
        for (int rep = 0; rep < 2; ++rep) {
            int idx = rep * 256 + tid; int tl = idx >> 3, c8 = idx & 7;
            *(short8*)&df[tl * 64 + c8 * 8] = *(const short8*)&sbuf[tl * 72 + c8 * 8];
        }
    }
}

// ---------------------------------------------------------------------------
// Kernel 2: fused null + foreground attention, COLUMN-SPLIT across 2
// wave-groups (512 threads, 8 waves). Fixed-shift softmax (m=0) makes
// partial (l, O) over disjoint column tiles trivially additive.
// vs round 1: (a) amdgpu_waves_per_eu(4) -> VGPR cap 128 not 64 (the 64-cap
// caused ~125 MB of scratch spill traffic = the whole regression);
// (b) null merge moved to immediately after phase 1, wg0 keeps NORMALIZED
// Onull in regs (drops lnull + unnormalized-keep -> ~round-0 reg footprint).
// ---------------------------------------------------------------------------
__global__ __launch_bounds__(512) __attribute__((amdgpu_waves_per_eu(4)))
void attn_fused(const short* __restrict__ wsS, const float* __restrict__ bboxes,
                float* __restrict__ out) {
    __shared__ __align__(16) short lds[27648];
    __shared__ unsigned short tmap[1024];
    __shared__ float lbuf[64];
    short* Ps = lds;            // [128][72] P rows (wave-private); Q staged rows 0..63; Ot aliases
    short* Ks = lds + 9216;     // [2][64][72]  ([s][c])
    short* Vs = lds + 18432;    // [2][64][72]  ([c][s]); fO1 (fp32 merge buf) aliases
    float* fO1 = (float*)(lds + 18432);   // [64][68] floats = 17408 B
    float* Ot  = (float*)lds;             // [64][68] floats (epilogue)

    int rt = blockIdx.x, bh = blockIdx.y;
    int b = bh >> 3, h = bh & 7;
    int t0 = rt * 64;
    int tid = threadIdx.x;
    int w = tid >> 6, lane = tid & 63, ln = lane & 15, qd = lane >> 4;
    int rw = w & 3;             // row-wave: rows 16*rw .. 16*rw+15
    int wg = w >> 2;            // column group: 0 = even tiles, 1 = odd tiles
    const short* QnT = wsS + QNT_OFF + bh * NT;
    const short* KnT = wsS + KNT_OFF + bh * NT;
    const short* Vn  = wsS + VNCS_OFF + bh * NT;
    const short* QfT = wsS + QFT_OFF + bh * NT;
    const short* KfT = wsS + KFT_OFF + bh * NT;
    const short* VfT = wsS + VFT_OFF + bh * NT;
    int scell = tid >> 3, sc8 = tid & 7;   // staging coords: cell 0..63, chunk 0..7
    short* Kb = Ks + wg * 4608;            // this wave-group's K buffer
    short* Vb = Vs + wg * 4608;            // this wave-group's V buffer

    // ================= Phase 1: null attention =================
    *(short8*)&Ps[scell * 72 + sc8 * 8] = *(const short8*)&QnT[(t0 + scell) * 64 + sc8 * 8];
    __syncthreads();
    short8 aq0 = *(const short8*)&Ps[(16 * rw + ln) * 72 + qd * 8];
    short8 aq1 = *(const short8*)&Ps[(16 * rw + ln) * 72 + 32 + qd * 8];
    v4f O[4]; float l[4];
#pragma unroll
    for (int r = 0; r < 4; ++r) l[r] = 0.f;
#pragma unroll
    for (int cc = 0; cc < 4; ++cc) O[cc] = (v4f){0.f, 0.f, 0.f, 0.f};
    short8 kreg[2], vreg[2];
    kreg[0] = *(const short8*)&KnT[scell * 64 + sc8 * 8];
    kreg[1] = *(const short8*)&KnT[(64 + scell) * 64 + sc8 * 8];
    vreg[0] = *(const short8*)&Vn[scell * TT + sc8 * 8];
    vreg[1] = *(const short8*)&Vn[scell * TT + 64 + sc8 * 8];
    for (int it = 0; it < 8; ++it) {        // 2 tiles per iteration (one per wg)
        __syncthreads();
        *(short8*)&Ks[scell * 72 + sc8 * 8]        = kreg[0];
        *(short8*)&Ks[4608 + scell * 72 + sc8 * 8] = kreg[1];
        *(short8*)&Vs[scell * 72 + sc8 * 8]        = vreg[0];   // Vn already [c][t]
        *(short8*)&Vs[4608 + scell * 72 + sc8 * 8] = vreg[1];
        __syncthreads();
        if (it < 7) {
            int s0 = (it + 1) * 128;
            kreg[0] = *(const short8*)&KnT[(s0 + scell) * 64 + sc8 * 8];
            kreg[1] = *(const short8*)&KnT[(s0 + 64 + scell) * 64 + sc8 * 8];
            vreg[0] = *(const short8*)&Vn[scell * TT + s0 + sc8 * 8];
            vreg[1] = *(const short8*)&Vn[scell * TT + s0 + 64 + sc8 * 8];
        }
        v4f S[4];
#pragma unroll
        for (int nn = 0; nn < 4; ++nn) {
            short8 b0 = *(const short8*)&Kb[(nn * 16 + ln) * 72 + qd * 8];
            short8 b1 = *(const short8*)&Kb[(nn * 16 + ln) * 72 + 32 + qd * 8];
            v4f z = (v4f){0.f, 0.f, 0.f, 0.f};
            z = __builtin_amdgcn_mfma_f32_16x16x32_bf16(aq0, b0, z, 0, 0, 0);
            z = __builtin_amdgcn_mfma_f32_16x16x32_bf16(aq1, b1, z, 0, 0, 0);
            S[nn] = z;
        }
#pragma unroll
        for (int r = 0; r < 4; ++r) {
            float e0 = __expf(S[0][r]);
            float e1 = __expf(S[1][r]);
            float e2 = __expf(S[2][r]);
            float e3 = __expf(S[3][r]);
            l[r] += e0 + e1 + e2 + e3;
            int prow = (w * 16 + 4 * qd + r) * 72;
            Ps[prow +  0 + ln] = f2bf(e0);
            Ps[prow + 16 + ln] = f2bf(e1);
            Ps[prow + 32 + ln] = f2bf(e2);
            Ps[prow + 48 + ln] = f2bf(e3);
        }
        short8 ap0 = *(const short8*)&Ps[(w * 16 + ln) * 72 + qd * 8];
        short8 ap1 = *(const short8*)&Ps[(w * 16 + ln) * 72 + 32 + qd * 8];
#pragma unroll
        for (int cc = 0; cc < 4; ++cc) {
            short8 bv0 = *(const short8*)&Vb[(cc * 16 + ln) * 72 + qd * 8];
            short8 bv1 = *(const short8*)&Vb[(cc * 16 + ln) * 72 + 32 + qd * 8];
            O[cc] = __builtin_amdgcn_mfma_f32_16x16x32_bf16(ap0, bv0, O[cc], 0, 0, 0);
            O[cc] = __builtin_amdgcn_mfma_f32_16x16x32_bf16(ap1, bv1, O[cc], 0, 0, 0);
        }
    }
    // ---- null merge NOW: wg1 dumps partials, wg0 keeps normalized Onull ----
    v4f Onull[4];
#pragma unroll
    for (int cc = 0; cc < 4; ++cc) Onull[cc] = (v4f){0.f, 0.f, 0.f, 0.f};
    {
        float lsum[4];
#pragma unroll
        for (int r = 0; r < 4; ++r) lsum[r] = rowsum16(l[r]);
        __syncthreads();
        if (wg == 1) {
#pragma unroll
            for (int r = 0; r < 4; ++r) {
                int row = 16 * rw + 4 * qd + r;
                if (ln == 0) lbuf[row] = lsum[r];
#pragma unroll
                for (int cc = 0; cc < 4; ++cc)
                    fO1[row * 68 + cc * 16 + ln] = O[cc][r];
            }
        }
        __syncthreads();
        if (wg == 0) {
#pragma unroll
            for (int r = 0; r < 4; ++r) {
                int row = 16 * rw + 4 * qd + r;
                float inv = 1.0f / (lsum[r] + lbuf[row]);
#pragma unroll
                for (int cc = 0; cc < 4; ++cc)
                    Onull[cc][r] = (O[cc][r] + fO1[row * 68 + cc * 16 + ln]) * inv;
            }
        }
    }

    // ================= Phase 2: foreground objects =================
    __syncthreads();
    *(short8*)&Ps[scell * 72 + sc8 * 8] = *(const short8*)&QfT[(t0 + scell) * 64 + sc8 * 8];
    __syncthreads();
    aq0 = *(const short8*)&Ps[(16 * rw + ln) * 72 + qd * 8];
    aq1 = *(const short8*)&Ps[(16 * rw + ln) * 72 + 32 + qd * 8];
    v4f Oacc[4]; float cnt[4];
#pragma unroll
    for (int r = 0; r < 4; ++r) cnt[r] = 0.f;
#pragma unroll
    for (int cc = 0; cc < 4; ++cc) Oacc[cc] = (v4f){0.f, 0.f, 0.f, 0.f};

    for (int o = 0; o < NOBJ; ++o) {
        int i0, j0, hh, ww;
        get_region(&bboxes[(b * NOBJ + o) * 5], i0, j0, hh, ww);
        int i1 = i0 + hh;
        if (i0 > 2 * rt + 1 || i1 <= 2 * rt) continue;   // uniform per block
        int R = hh * ww;
        for (int idx = tid; idx < R; idx += 512) {
            int ri = idx / ww; int rj = idx - ri * ww;
            tmap[idx] = (unsigned short)((i0 + ri) * 32 + j0 + rj);
        }
        __syncthreads();
#pragma unroll
        for (int r = 0; r < 4; ++r) l[r] = 0.f;
#pragma unroll
        for (int cc = 0; cc < 4; ++cc) O[cc] = (v4f){0.f, 0.f, 0.f, 0.f};
        int nct = (R + 63) >> 6;
        int npair = (nct + 1) >> 1;     // wg1's extra tile (odd nct) fully masked
        {
            int tA = tmap[min(scell, R - 1)];
            int tB = tmap[min(64 + scell, R - 1)];
            kreg[0] = *(const short8*)&KfT[tA * 64 + sc8 * 8];
            kreg[1] = *(const short8*)&KfT[tB * 64 + sc8 * 8];
            vreg[0] = *(const short8*)&VfT[tA * 64 + sc8 * 8];
            vreg[1] = *(const short8*)&VfT[tB * 64 + sc8 * 8];
        }
        for (int p = 0; p < npair; ++p) {
            int sbw = (2 * p + wg) * 64;     // this wave-group's col base
            __syncthreads();
            *(short8*)&Ks[scell * 72 + sc8 * 8]        = kreg[0];
            *(short8*)&Ks[4608 + scell * 72 + sc8 * 8] = kreg[1];
            // rotated transpose scatter into Vs [c][s] (bank-conflict-free)
#pragma unroll
            for (int jj = 0; jj < 8; ++jj) {
                int j = (jj + sc8) & 7;
                Vs[(sc8 * 8 + j) * 72 + scell] = vreg[0][j];
            }
#pragma unroll
            for (int jj = 0; jj < 8; ++jj) {
                int j = (jj + sc8) & 7;
                Vs[4608 + (sc8 * 8 + j) * 72 + scell] = vreg[1][j];
            }
            __syncthreads();
            if (p + 1 < npair) {
                int s0 = (2 * p + 2) * 64;
                int tA = tmap[min(s0 + scell, R - 1)];
                int tB = tmap[min(s0 + 64 + scell, R - 1)];
                kreg[0] = *(const short8*)&KfT[tA * 64 + sc8 * 8];
                kreg[1] = *(const short8*)&KfT[tB * 64 + sc8 * 8];
                vreg[0] = *(const short8*)&VfT[tA * 64 + sc8 * 8];
                vreg[1] = *(const short8*)&VfT[tB * 64 + sc8 * 8];
            }
            v4f S[4];
#pragma unroll
            for (int nn = 0; nn < 4; ++nn) {
                short8 b0 = *(const short8*)&Kb[(nn * 16 + ln) * 72 + qd * 8];
                short8 b1 = *(const short8*)&Kb[(nn * 16 + ln) * 72 + 32 + qd * 8];
                v4f z = (v4f){0.f, 0.f, 0.f, 0.f};
                z = __builtin_amdgcn_mfma_f32_16x16x32_bf16(aq0, b0, z, 0, 0, 0);
                z = __builtin_amdgcn_mfma_f32_16x16x32_bf16(aq1, b1, z, 0, 0, 0);
                S[nn] = z;
            }
            float v0 = (sbw +  0 + ln) < R ? 1.f : 0.f;
            float v1 = (sbw + 16 + ln) < R ? 1.f : 0.f;
            float v2 = (sbw + 32 + ln) < R ? 1.f : 0.f;
            float v3 = (sbw + 48 + ln) < R ? 1.f : 0.f;
#pragma unroll
            for (int r = 0; r < 4; ++r) {
                float e0 = __expf(S[0][r]) * v0;
                float e1 = __expf(S[1][r]) * v1;
                float e2 = __expf(S[2][r]) * v2;
                float e3 = __expf(S[3][r]) * v3;
                l[r] += e0 + e1 + e2 + e3;
                int prow = (w * 16 + 4 * qd + r) * 72;
                Ps[prow +  0 + ln] = f2bf(e0);
                Ps[prow + 16 + ln] = f2bf(e1);
                Ps[prow + 32 + ln] = f2bf(e2);
                Ps[prow + 48 + ln] = f2bf(e3);
            }
            short8 ap0 = *(const short8*)&Ps[(w * 16 + ln) * 72 + qd * 8];
            short8 ap1 = *(const short8*)&Ps[(w * 16 + ln) * 72 + 32 + qd * 8];
#pragma unroll
            for (int cc = 0; cc < 4; ++cc) {
                short8 bv0 = *(const short8*)&Vb[(cc * 16 + ln) * 72 + qd * 8];
                short8 bv1 = *(const short8*)&Vb[(cc * 16 + ln) * 72 + 32 + qd * 8];
                O[cc] = __builtin_amdgcn_mfma_f32_16x16x32_bf16(ap0, bv0, O[cc], 0, 0, 0);
                O[cc] = __builtin_amdgcn_mfma_f32_16x16x32_bf16(ap1, bv1, O[cc], 0, 0, 0);
            }
        }
        // cross-wg merge: wg1 dumps partials, wg0 normalizes & accumulates
        __syncthreads();
        if (wg == 1) {
#pragma unroll
            for (int r = 0; r < 4; ++r) {
                float rs = rowsum16(l[r]);
                int row = 16 * rw + 4 * qd + r;
                if (ln == 0) lbuf[row] = rs;
#pragma unroll
                for (int cc = 0; cc < 4; ++cc)
                    fO1[row * 68 + cc * 16 + ln] = O[cc][r];
            }
        }
        __syncthreads();
        if (wg == 0) {
#pragma unroll
            for (int r = 0; r < 4; ++r) {
                int row = 16 * rw + 4 * qd + r;
                float rs = rowsum16(l[r]) + lbuf[row];
                float inv = 1.0f / rs;
                int t = t0 + row;
                int ti = t >> 5, tj = t & 31;
                bool in = (ti >= i0) && (ti < i1) && (tj >= j0) && (tj < j0 + ww);
                if (in) {
                    cnt[r] += 1.f;
#pragma unroll
                    for (int cc = 0; cc < 4; ++cc)
                        Oacc[cc][r] += (O[cc][r] + fO1[row * 68 + cc * 16 + ln]) * inv;
                }
            }
        }
    }

    // ================= Epilogue: final select + write =================
    __syncthreads();
    if (wg == 0) {
#pragma unroll
        for (int r = 0; r < 4; ++r) {
            int row = 16 * rw + 4 * qd + r;
            bool fg = cnt[r] > 0.f;
            float icnt = fg ? 1.0f / cnt[r] : 0.f;
#pragma unroll
            for (int cc = 0; cc < 4; ++cc) {
                float val = fg ? Oacc[cc][r] * icnt : Onull[cc][r];
                Ot[(cc * 16 + ln) * 68 + row] = val;
            }
        }
    }
    __syncthreads();
    int obase = (b * 512 + h * 64) * TT + t0;
#pragma unroll
    for (int rep = 0; rep < 2; ++rep) {
        int idx = rep * 512 + tid; int c = idx >> 4, t4 = (idx & 15) * 4;
        *(float4*)&out[obase + c * TT + t4] = *(float4*)&Ot[c * 68 + t4];
    }
}

extern "C" void kernel_launch(void* const* d_in, const int* in_sizes, int n_in,
                              void* d_out, int out_size, void* d_ws, size_t ws_size,
                              hipStream_t stream) {
    const float* qkv    = (const float*)d_in[0];
    const float* bboxes = (const float*)d_in[1];
    const float* nEmb   = (const float*)d_in[2];
    const float* pEmb   = (const float*)d_in[3];
    const float* W      = (const float*)d_in[4];
    short* wsS = (short*)d_ws;
    float* out = (float*)d_out;

    fuse_kernel<<<dim3(16, 24, 4), 256, 0, stream>>>(qkv, nEmb, pEmb, W, wsS);
    attn_fused<<<dim3(16, 32), 512, 0, stream>>>(wsS, bboxes, out);
}

// Round 4
// 154.364 us; speedup vs baseline: 1.3301x; 1.3230x over previous
//
#include <hip/hip_runtime.h>

// Problem constants (fixed by setup_inputs)
#define BS 4
#define NH 8
#define TT 1024         // T = 32*32
#define WROWS 1536      // 3*NH*CH
#define NOBJ 8
#define NT 65536        // per-bh tensor elems (64*1024)

// Workspace layout (short element offsets)
#define QNT_OFF  0
#define KNT_OFF  2097152
#define VNCS_OFF 4194304
#define QFT_OFF  6291456
#define KFT_OFF  8388608
#define VFT_OFF  10485760

typedef __attribute__((ext_vector_type(8))) short short8;
typedef __attribute__((ext_vector_type(4))) float v4f;

__device__ __forceinline__ short f2bf(float f) {
    unsigned u = __float_as_uint(f);
    u = (u + 0x7FFF + ((u >> 16) & 1)) >> 16;   // RNE
    return (short)u;
}
// packed f32x2 -> bf16x2 (RNE), lo = a, hi = b
__device__ __forceinline__ unsigned cvtpk(float a, float b) {
    unsigned u;
    asm("v_cvt_pk_bf16_f32 %0, %1, %2" : "=v"(u) : "v"(a), "v"(b));
    return u;
}
// 2^x via the HW transcendental (avoids glibc __exp2f name clash)
__device__ __forceinline__ float fexp2(float x) {
    float r;
    asm("v_exp_f32 %0, %1" : "=v"(r) : "v"(x));
    return r;
}
// pi-permutation of s-position within a 64-tile: s -> 4*(s&15) + (s>>4).
// P is stored with column c' = pi(s); V tiles are staged with the same
// column order so the PV contraction stays consistent.
__device__ __forceinline__ int pi64(int s) { return 4 * (s & 15) + (s >> 4); }

__device__ __forceinline__ void get_region(const float* __restrict__ bb,
                                           int& i0, int& j0, int& hh, int& ww) {
    float x = bb[0], y = bb[1], bw = bb[2], bh = bb[3];
    float i0f = fminf(31.0f, floorf(y * 32.0f));
    float j0f = fminf(31.0f, floorf(x * 32.0f));
    float i1f = i0f + fmaxf(1.0f, ceilf(bh * 32.0f));
    float j1f = j0f + fmaxf(1.0f, ceilf(bw * 32.0f));
    i0 = (int)i0f; j0 = (int)j0f;
    int i1 = min(32, (int)i1f);
    int j1 = min(32, (int)j1f);
    hh = i1 - i0; ww = j1 - j0;
}

// ---------------------------------------------------------------------------
// Kernel 1: fused projection + layout conversion to bf16.
// q scaled by 0.125*log2(e) so attention can use exp2 directly.
// null V is written PRE-PERMUTED per 64-tile: VnP[c][64k + pi(p)] = V[c][64k+p]
// so attn's vectorized null staging directly yields the pi-ordered Vs.
// ---------------------------------------------------------------------------
__global__ __launch_bounds__(256)
void fuse_kernel(const float* __restrict__ qkv, const float* __restrict__ nEmb,
                 const float* __restrict__ pEmb, const float* __restrict__ W,
                 short* __restrict__ wsS) {
    __shared__ float WtT[64][68];
    __shared__ float En[64][64];
    __shared__ float Ep[64][64];
    short* sbuf = (short*)&WtT[0][0];   // 64x72 shorts = 9216 B, aliases WtT
    int t0 = blockIdx.x * 64;
    int r0 = blockIdx.y * 64;
    int b  = blockIdx.z;
    int tid = threadIdx.x;
    int half = tid >> 4;
    int q4 = (tid & 15) * 4;
#pragma unroll
    for (int p = 0; p < 4; ++p) {
        int rr = p * 16 + half;
        float4 w4 = *(const float4*)&W[(r0 + rr) * 64 + q4];
        WtT[q4 + 0][rr] = w4.x; WtT[q4 + 1][rr] = w4.y;
        WtT[q4 + 2][rr] = w4.z; WtT[q4 + 3][rr] = w4.w;
        int e = p * 16 + half;
        *(float4*)&En[e][q4] = *(const float4*)&nEmb[(b * 64 + e) * TT + t0 + q4];
        *(float4*)&Ep[e][q4] = *(const float4*)&pEmb[(b * 64 + e) * TT + t0 + q4];
    }
    __syncthreads();
    int tr = tid >> 4, tc = tid & 15;
    float an[4][4] = {{0.f}}, ap[4][4] = {{0.f}};
#pragma unroll 8
    for (int e = 0; e < 64; ++e) {
        float4 w4 = *(const float4*)&WtT[e][tr * 4];
        float4 n4 = *(const float4*)&En[e][tc * 4];
        float4 p4 = *(const float4*)&Ep[e][tc * 4];
        float w[4]  = {w4.x, w4.y, w4.z, w4.w};
        float nn[4] = {n4.x, n4.y, n4.z, n4.w};
        float pp[4] = {p4.x, p4.y, p4.z, p4.w};
#pragma unroll
        for (int i = 0; i < 4; ++i)
#pragma unroll
            for (int j = 0; j < 4; ++j) {
                an[i][j] += w[i] * nn[j];
                ap[i][j] += w[i] * pp[j];
            }
    }
    int sec = (r0 % 192) / 64;          // 0=q 1=k 2=v
    int h = r0 / 192, bh = b * 8 + h;
    // fold scale^2 AND log2(e) into Q (attn uses exp2)
    float sc = (sec == 0) ? 0.18033688f : 1.0f;
#pragma unroll
    for (int i = 0; i < 4; ++i) {
        int r = r0 + tr * 4 + i;
        float4 x4 = *(const float4*)&qkv[(b * WROWS + r) * TT + t0 + tc * 4];
        an[i][0] = (an[i][0] + x4.x) * sc; an[i][1] = (an[i][1] + x4.y) * sc;
        an[i][2] = (an[i][2] + x4.z) * sc; an[i][3] = (an[i][3] + x4.w) * sc;
        ap[i][0] = (ap[i][0] + x4.x) * sc; ap[i][1] = (ap[i][1] + x4.y) * sc;
        ap[i][2] = (ap[i][2] + x4.z) * sc; ap[i][3] = (ap[i][3] + x4.w) * sc;
    }
    if (sec == 2) {
        // pass 1: null V, pre-permuted [c][pi(p)] within each 64-tile
        short* Vn = wsS + VNCS_OFF + bh * NT;
        __syncthreads();
#pragma unroll
        for (int i = 0; i < 4; ++i)
#pragma unroll
            for (int j = 0; j < 4; ++j) {
                int p = tc * 4 + j;
                sbuf[(tr * 4 + i) * 72 + pi64(p)] = f2bf(an[i][j]);
            }
        __syncthreads();
#pragma unroll
        for (int rep = 0; rep < 2; ++rep) {
            int idx = rep * 256 + tid; int cl = idx >> 3, c8 = idx & 7;
            *(short8*)&Vn[cl * TT + t0 + c8 * 8] = *(const short8*)&sbuf[cl * 72 + c8 * 8];
        }
        // pass 2: fg V transposed [t][c]
        short* dst = wsS + VFT_OFF + bh * NT + t0 * 64;
        __syncthreads();
#pragma unroll
        for (int j = 0; j < 4; ++j) {
            uint2 u; u.x = cvtpk(ap[0][j], ap[1][j]); u.y = cvtpk(ap[2][j], ap[3][j]);
            *(uint2*)&sbuf[(tc * 4 + j) * 72 + tr * 4] = u;
        }
        __syncthreads();
#pragma unroll
        for (int rep = 0; rep < 2; ++rep) {
            int idx = rep * 256 + tid; int tl = idx >> 3, c8 = idx & 7;
            *(short8*)&dst[tl * 64 + c8 * 8] = *(const short8*)&sbuf[tl * 72 + c8 * 8];
        }
    } else {
        short* dn = wsS + (sec == 0 ? QNT_OFF : KNT_OFF) + bh * NT + t0 * 64;
        short* df = wsS + (sec == 0 ? QFT_OFF : KFT_OFF) + bh * NT + t0 * 64;
        __syncthreads();
#pragma unroll
        for (int j = 0; j < 4; ++j) {
            uint2 u; u.x = cvtpk(an[0][j], an[1][j]); u.y = cvtpk(an[2][j], an[3][j]);
            *(uint2*)&sbuf[(tc * 4 + j) * 72 + tr * 4] = u;
        }
        __syncthreads();
#pragma unroll
        for (int rep = 0; rep < 2; ++rep) {
            int idx = rep * 256 + tid; int tl = idx >> 3, c8 = idx & 7;
            *(short8*)&dn[tl * 64 + c8 * 8] = *(const short8*)&sbuf[tl * 72 + c8 * 8];
        }
        __syncthreads();
#pragma unroll
        for (int j = 0; j < 4; ++j) {
            uint2 u; u.x = cvtpk(ap[0][j], ap[1][j]); u.y = cvtpk(ap[2][j], ap[3][j]);
            *(uint2*)&sbuf[(tc * 4 + j) * 72 + tr * 4] = u;
        }
        __syncthreads();
#pragma unroll
        for (int rep = 0; rep < 2; ++rep) {
            int idx = rep * 256 + tid; int tl = idx >> 3, c8 = idx & 7;
            *(short8*)&df[tl * 64 + c8 * 8] = *(const short8*)&sbuf[tl * 72 + c8 * 8];
        }
    }
}

// ---------------------------------------------------------------------------
// Kernel 2: fused null + foreground attention (round-0 structure: 256 thr,
// 4 waves, no spill). Changes vs round-0:
//  - v_exp_f32 (2^x) instead of expf (log2e folded into Q at fuse time)
//  - P stored in pi-permuted columns: lane's 4 nn-values contiguous ->
//    2x v_cvt_pk_bf16_f32 + 1x ds_write_b64 per row (was 16 VALU-heavy
//    scalar b16 stores). V tiles staged in matching pi order.
// ---------------------------------------------------------------------------
__global__ __launch_bounds__(256)
void attn_fused(const short* __restrict__ wsS, const float* __restrict__ bboxes,
                float* __restrict__ out) {
    __shared__ __align__(16) short lds[13824];
    __shared__ unsigned short tmap[1024];
    short* Qs = lds;            // [64][72], aliased as Ps (wave-private rows)
    short* Ks = lds + 4608;     // [64][72]  ([s][c])
    short* Vs = lds + 9216;     // [64][72]  ([c][pi(s)])
    int rt = blockIdx.x, bh = blockIdx.y;
    int b = bh >> 3, h = bh & 7;
    int t0 = rt * 64;
    int tid = threadIdx.x;
    int w = tid >> 6, lane = tid & 63, ln = lane & 15, qd = lane >> 4;
    const short* QnT = wsS + QNT_OFF + bh * NT;
    const short* KnT = wsS + KNT_OFF + bh * NT;
    const short* Vn  = wsS + VNCS_OFF + bh * NT;   // pre-permuted [c][pi]
    const short* QfT = wsS + QFT_OFF + bh * NT;
    const short* KfT = wsS + KFT_OFF + bh * NT;
    const short* VfT = wsS + VFT_OFF + bh * NT;
    int sidx = tid, scell = sidx >> 3, sc8 = sidx & 7;      // staging coords lo
    int sidx2 = 256 + tid, scell2 = sidx2 >> 3, sc82 = sidx2 & 7;

    // ================= Phase 1: null attention =================
    *(short8*)&Qs[scell * 72 + sc8 * 8]  = *(const short8*)&QnT[(t0 + scell) * 64 + sc8 * 8];
    *(short8*)&Qs[scell2 * 72 + sc82 * 8] = *(const short8*)&QnT[(t0 + scell2) * 64 + sc82 * 8];
    __syncthreads();
    short8 aq0 = *(const short8*)&Qs[(16 * w + ln) * 72 + qd * 8];
    short8 aq1 = *(const short8*)&Qs[(16 * w + ln) * 72 + 32 + qd * 8];
    v4f O[4]; float l[4];
#pragma unroll
    for (int r = 0; r < 4; ++r) l[r] = 0.f;
#pragma unroll
    for (int cc = 0; cc < 4; ++cc) O[cc] = (v4f){0.f, 0.f, 0.f, 0.f};
    short8 kreg[2], vreg[2];
    kreg[0] = *(const short8*)&KnT[scell * 64 + sc8 * 8];
    kreg[1] = *(const short8*)&KnT[scell2 * 64 + sc82 * 8];
    vreg[0] = *(const short8*)&Vn[scell * TT + sc8 * 8];
    vreg[1] = *(const short8*)&Vn[scell2 * TT + sc82 * 8];
    for (int ct = 0; ct < 16; ++ct) {
        __syncthreads();
        *(short8*)&Ks[scell * 72 + sc8 * 8]  = kreg[0];
        *(short8*)&Ks[scell2 * 72 + sc82 * 8] = kreg[1];
        *(short8*)&Vs[scell * 72 + sc8 * 8]  = vreg[0];     // Vn already [c][pi]
        *(short8*)&Vs[scell2 * 72 + sc82 * 8] = vreg[1];
        __syncthreads();
        if (ct < 15) {
            int s0 = (ct + 1) * 64;
            kreg[0] = *(const short8*)&KnT[(s0 + scell) * 64 + sc8 * 8];
            kreg[1] = *(const short8*)&KnT[(s0 + scell2) * 64 + sc82 * 8];
            vreg[0] = *(const short8*)&Vn[scell * TT + s0 + sc8 * 8];
            vreg[1] = *(const short8*)&Vn[scell2 * TT + s0 + sc82 * 8];
        }
        v4f S[4];
#pragma unroll
        for (int nn = 0; nn < 4; ++nn) {
            short8 b0 = *(const short8*)&Ks[(nn * 16 + ln) * 72 + qd * 8];
            short8 b1 = *(const short8*)&Ks[(nn * 16 + ln) * 72 + 32 + qd * 8];
            v4f z = (v4f){0.f, 0.f, 0.f, 0.f};
            z = __builtin_amdgcn_mfma_f32_16x16x32_bf16(aq0, b0, z, 0, 0, 0);
            z = __builtin_amdgcn_mfma_f32_16x16x32_bf16(aq1, b1, z, 0, 0, 0);
            S[nn] = z;
        }
#pragma unroll
        for (int r = 0; r < 4; ++r) {
            float e0 = fexp2(S[0][r]);
            float e1 = fexp2(S[1][r]);
            float e2 = fexp2(S[2][r]);
            float e3 = fexp2(S[3][r]);
            l[r] += (e0 + e1) + (e2 + e3);
            uint2 u; u.x = cvtpk(e0, e1); u.y = cvtpk(e2, e3);
            *(uint2*)&Qs[(w * 16 + 4 * qd + r) * 72 + 4 * ln] = u;   // cols pi(s)
        }
        short8 ap0 = *(const short8*)&Qs[(w * 16 + ln) * 72 + qd * 8];
        short8 ap1 = *(const short8*)&Qs[(w * 16 + ln) * 72 + 32 + qd * 8];
#pragma unroll
        for (int cc = 0; cc < 4; ++cc) {
            short8 bv0 = *(const short8*)&Vs[(cc * 16 + ln) * 72 + qd * 8];
            short8 bv1 = *(const short8*)&Vs[(cc * 16 + ln) * 72 + 32 + qd * 8];
            O[cc] = __builtin_amdgcn_mfma_f32_16x16x32_bf16(ap0, bv0, O[cc], 0, 0, 0);
            O[cc] = __builtin_amdgcn_mfma_f32_16x16x32_bf16(ap1, bv1, O[cc], 0, 0, 0);
        }
    }
    v4f Onull[4];
#pragma unroll
    for (int r = 0; r < 4; ++r) {
        float rs = l[r];
        rs += __shfl_xor(rs, 1, 64);
        rs += __shfl_xor(rs, 2, 64);
        rs += __shfl_xor(rs, 4, 64);
        rs += __shfl_xor(rs, 8, 64);
        float inv = 1.0f / rs;
#pragma unroll
        for (int cc = 0; cc < 4; ++cc) Onull[cc][r] = O[cc][r] * inv;
    }

    // ================= Phase 2: foreground objects =================
    __syncthreads();
    *(short8*)&Qs[scell * 72 + sc8 * 8]  = *(const short8*)&QfT[(t0 + scell) * 64 + sc8 * 8];
    *(short8*)&Qs[scell2 * 72 + sc82 * 8] = *(const short8*)&QfT[(t0 + scell2) * 64 + sc82 * 8];
    __syncthreads();
    aq0 = *(const short8*)&Qs[(16 * w + ln) * 72 + qd * 8];
    aq1 = *(const short8*)&Qs[(16 * w + ln) * 72 + 32 + qd * 8];
    v4f Oacc[4]; float cnt[4];
#pragma unroll
    for (int r = 0; r < 4; ++r) cnt[r] = 0.f;
#pragma unroll
    for (int cc = 0; cc < 4; ++cc) Oacc[cc] = (v4f){0.f, 0.f, 0.f, 0.f};

    for (int o = 0; o < NOBJ; ++o) {
        int i0, j0, hh, ww;
        get_region(&bboxes[(b * NOBJ + o) * 5], i0, j0, hh, ww);
        int i1 = i0 + hh;
        if (i0 > 2 * rt + 1 || i1 <= 2 * rt) continue;   // uniform per block
        int R = hh * ww;
        for (int idx = tid; idx < R; idx += 256) {
            int ri = idx / ww; int rj = idx - ri * ww;
            tmap[idx] = (unsigned short)((i0 + ri) * 32 + j0 + rj);
        }
        __syncthreads();
#pragma unroll
        for (int r = 0; r < 4; ++r) l[r] = 0.f;
#pragma unroll
        for (int cc = 0; cc < 4; ++cc) O[cc] = (v4f){0.f, 0.f, 0.f, 0.f};
        int nct = (R + 63) >> 6;
        {
            int tA = tmap[min(scell, R - 1)];
            int tB = tmap[min(scell2, R - 1)];
            kreg[0] = *(const short8*)&KfT[tA * 64 + sc8 * 8];
            kreg[1] = *(const short8*)&KfT[tB * 64 + sc82 * 8];
            vreg[0] = *(const short8*)&VfT[tA * 64 + sc8 * 8];
            vreg[1] = *(const short8*)&VfT[tB * 64 + sc82 * 8];
        }
        int pA = pi64(scell), pB = pi64(scell2);
        for (int ct = 0; ct < nct; ++ct) {
            int sb = ct * 64;
            __syncthreads();
            *(short8*)&Ks[scell * 72 + sc8 * 8]  = kreg[0];
            *(short8*)&Ks[scell2 * 72 + sc82 * 8] = kreg[1];
            // rotated transpose scatter into Vs [c][pi(s)]
#pragma unroll
            for (int jj = 0; jj < 8; ++jj) {
                int j = (jj + sc8) & 7;
                Vs[(sc8 * 8 + j) * 72 + pA] = vreg[0][j];
            }
#pragma unroll
            for (int jj = 0; jj < 8; ++jj) {
                int j = (jj + sc82) & 7;
                Vs[(sc82 * 8 + j) * 72 + pB] = vreg[1][j];
            }
            __syncthreads();
            if (ct + 1 < nct) {
                int s0 = sb + 64;
                int tA = tmap[min(s0 + scell, R - 1)];
                int tB = tmap[min(s0 + scell2, R - 1)];
                kreg[0] = *(const short8*)&KfT[tA * 64 + sc8 * 8];
                kreg[1] = *(const short8*)&KfT[tB * 64 + sc82 * 8];
                vreg[0] = *(const short8*)&VfT[tA * 64 + sc8 * 8];
                vreg[1] = *(const short8*)&VfT[tB * 64 + sc82 * 8];
            }
            v4f S[4];
#pragma unroll
            for (int nn = 0; nn < 4; ++nn) {
                short8 b0 = *(const short8*)&Ks[(nn * 16 + ln) * 72 + qd * 8];
                short8 b1 = *(const short8*)&Ks[(nn * 16 + ln) * 72 + 32 + qd * 8];
                v4f z = (v4f){0.f, 0.f, 0.f, 0.f};
                z = __builtin_amdgcn_mfma_f32_16x16x32_bf16(aq0, b0, z, 0, 0, 0);
                z = __builtin_amdgcn_mfma_f32_16x16x32_bf16(aq1, b1, z, 0, 0, 0);
                S[nn] = z;
            }
            float v0 = (sb +  0 + ln) < R ? 1.f : 0.f;
            float v1 = (sb + 16 + ln) < R ? 1.f : 0.f;
            float v2 = (sb + 32 + ln) < R ? 1.f : 0.f;
            float v3 = (sb + 48 + ln) < R ? 1.f : 0.f;
#pragma unroll
            for (int r = 0; r < 4; ++r) {
                float e0 = fexp2(S[0][r]) * v0;
                float e1 = fexp2(S[1][r]) * v1;
                float e2 = fexp2(S[2][r]) * v2;
                float e3 = fexp2(S[3][r]) * v3;
                l[r] += (e0 + e1) + (e2 + e3);
                uint2 u; u.x = cvtpk(e0, e1); u.y = cvtpk(e2, e3);
                *(uint2*)&Qs[(w * 16 + 4 * qd + r) * 72 + 4 * ln] = u;
            }
            short8 ap0 = *(const short8*)&Qs[(w * 16 + ln) * 72 + qd * 8];
            short8 ap1 = *(const short8*)&Qs[(w * 16 + ln) * 72 + 32 + qd * 8];
#pragma unroll
            for (int cc = 0; cc < 4; ++cc) {
                short8 bv0 = *(const short8*)&Vs[(cc * 16 + ln) * 72 + qd * 8];
                short8 bv1 = *(const short8*)&Vs[(cc * 16 + ln) * 72 + 32 + qd * 8];
                O[cc] = __builtin_amdgcn_mfma_f32_16x16x32_bf16(ap0, bv0, O[cc], 0, 0, 0);
                O[cc] = __builtin_amdgcn_mfma_f32_16x16x32_bf16(ap1, bv1, O[cc], 0, 0, 0);
            }
        }
        // finalize object: accumulate rows inside region
#pragma unroll
        for (int r = 0; r < 4; ++r) {
            float rs = l[r];
            rs += __shfl_xor(rs, 1, 64);
            rs += __shfl_xor(rs, 2, 64);
            rs += __shfl_xor(rs, 4, 64);
            rs += __shfl_xor(rs, 8, 64);
            float inv = 1.0f / rs;
            int t = t0 + 16 * w + 4 * qd + r;
            int ti = t >> 5, tj = t & 31;
            bool in = (ti >= i0) && (ti < i1) && (tj >= j0) && (tj < j0 + ww);
            if (in) {
                cnt[r] += 1.f;
#pragma unroll
                for (int cc = 0; cc < 4; ++cc) Oacc[cc][r] += O[cc][r] * inv;
            }
        }
    }

    // ================= Epilogue =================
    __syncthreads();
    float* Ot = (float*)lds;   // [64][68] floats = 17408 B (fits in 27648 B)
#pragma unroll
    for (int r = 0; r < 4; ++r) {
        int tl = 16 * w + 4 * qd + r;
        float icnt = cnt[r] > 0.f ? 1.0f / cnt[r] : 0.f;
#pragma unroll
        for (int cc = 0; cc < 4; ++cc) {
            float val = cnt[r] > 0.f ? Oacc[cc][r] * icnt : Onull[cc][r];
            Ot[(cc * 16 + ln) * 68 + tl] = val;
        }
    }
    __syncthreads();
    int obase = (b * 512 + h * 64) * TT + t0;
#pragma unroll
    for (int rep = 0; rep < 4; ++rep) {
        int idx = rep * 256 + tid; int c = idx >> 4, t4 = (idx & 15) * 4;
        *(float4*)&out[obase + c * TT + t4] = *(float4*)&Ot[c * 68 + t4];
    }
}

extern "C" void kernel_launch(void* const* d_in, const int* in_sizes, int n_in,
                              void* d_out, int out_size, void* d_ws, size_t ws_size,
                              hipStream_t stream) {
    const float* qkv    = (const float*)d_in[0];
    const float* bboxes = (const float*)d_in[1];
    const float* nEmb   = (const float*)d_in[2];
    const float* pEmb   = (const float*)d_in[3];
    const float* W      = (const float*)d_in[4];
    short* wsS = (short*)d_ws;
    float* out = (float*)d_out;

    fuse_kernel<<<dim3(16, 24, 4), 256, 0, stream>>>(qkv, nEmb, pEmb, W, wsS);
    attn_fused<<<dim3(16, 32), 256, 0, stream>>>(wsS, bboxes, out);
}